// Round 13
// baseline (236.706 us; speedup 1.0000x reference)
//
#include <hip/hip_runtime.h>

#define HW 3136
#define CH 256
#define NJT 49
#define NPIX 25088  // 8*3136

typedef __attribute__((ext_vector_type(8))) short bf16x8;
typedef __attribute__((ext_vector_type(4))) float f32x4;
typedef __attribute__((ext_vector_type(16))) float f32x16;
typedef unsigned short u16;
typedef unsigned int u32;

static __device__ __forceinline__ u16 f2bf(float f){
  union { float f; u32 u; } v; v.f = f;
  u32 r = v.u + 0x7FFFu + ((v.u >> 16) & 1u);
  return (u16)(r >> 16);
}

static __device__ __forceinline__ void gload16(const void* g, void* l){
  __builtin_amdgcn_global_load_lds(
      (const __attribute__((address_space(1))) unsigned int*)g,
      (__attribute__((address_space(3))) unsigned int*)l, 16, 0, 0);
}

static __device__ __forceinline__ f32x16 zero16(){
  f32x16 v;
  #pragma unroll
  for (int e = 0; e < 16; ++e) v[e] = 0.f;
  return v;
}

#define MFMA32(A,B,C) __builtin_amdgcn_mfma_f32_32x32x16_bf16((A),(B),(C),0,0,0)

// ---------- prep: W (CxC fp32, [cin][cout]) -> Wt bf16 [cout][cin] ----------
__global__ __launch_bounds__(256) void prep_wt(const float* __restrict__ W,
                                               u16* __restrict__ Wt){
  const int o = blockIdx.x, i = threadIdx.x;
  Wt[o*CH + i] = f2bf(W[i*CH + o]);
}

// ---------- fused: row-norm (fp32) + xn emit + t = x @ W stored transposed tT[b][c][j] ----------
__global__ __launch_bounds__(256) void gemm_t(const float* __restrict__ x,
                                              const u16* __restrict__ Wt,
                                              u16* __restrict__ xn_bf,
                                              u16* __restrict__ tT){
  __shared__ u16 sT[256*64];  // [c][j-chunk swizzled]
  const int jt = blockIdx.x, b = blockIdx.y;
  const int tid = threadIdx.x, wid = tid >> 6, lane = tid & 63;
  const int l15 = lane & 15, l4 = lane >> 4;
  const int j0 = jt * 64;
  const int row = j0 + wid*16 + l15;
  const float* xp = x + ((size_t)b*HW + row)*CH + l4*8;

  float xv[8][8];
  float ss = 0.f;
  #pragma unroll
  for (int kb = 0; kb < 8; ++kb){
    const float4 v0 = *(const float4*)(xp + kb*32);
    const float4 v1 = *(const float4*)(xp + kb*32 + 4);
    xv[kb][0]=v0.x; xv[kb][1]=v0.y; xv[kb][2]=v0.z; xv[kb][3]=v0.w;
    xv[kb][4]=v1.x; xv[kb][5]=v1.y; xv[kb][6]=v1.z; xv[kb][7]=v1.w;
    #pragma unroll
    for (int e = 0; e < 8; ++e) ss += xv[kb][e]*xv[kb][e];
  }
  ss += __shfl_xor(ss, 16);
  ss += __shfl_xor(ss, 32);
  const float inv = rsqrtf(fmaxf(ss, 1e-12f));

  bf16x8 ax[8];
  #pragma unroll
  for (int kb = 0; kb < 8; ++kb){
    bf16x8 a, n;
    #pragma unroll
    for (int e = 0; e < 8; ++e){
      a[e] = (short)f2bf(xv[kb][e]);
      n[e] = (short)f2bf(xv[kb][e]*inv);
    }
    ax[kb] = a;
    *(bf16x8*)(xn_bf + ((size_t)b*HW + row)*CH + kb*32 + l4*8) = n;
  }

  f32x4 acc[16];
  #pragma unroll
  for (int n = 0; n < 16; ++n) acc[n] = f32x4{0.f,0.f,0.f,0.f};
  #pragma unroll
  for (int kb = 0; kb < 8; ++kb){
    #pragma unroll
    for (int n0 = 0; n0 < 16; ++n0){
      const bf16x8 bb = *(const bf16x8*)(Wt + (n0*16 + l15)*CH + kb*32 + l4*8);
      acc[n0] = __builtin_amdgcn_mfma_f32_16x16x32_bf16(ax[kb], bb, acc[n0], 0, 0, 0);
    }
  }
  #pragma unroll
  for (int n0 = 0; n0 < 16; ++n0){
    const int c = n0*16 + l15;
    const int jloc = wid*16 + l4*4;
    const int gj = jloc >> 3;
    ushort4 w4;
    w4.x = f2bf(acc[n0][0]); w4.y = f2bf(acc[n0][1]);
    w4.z = f2bf(acc[n0][2]); w4.w = f2bf(acc[n0][3]);
    *(ushort4*)&sT[c*64 + ((gj ^ (c & 7)) * 8) + (jloc & 7)] = w4;
  }
  __syncthreads();
  #pragma unroll
  for (int p = 0; p < 8; ++p){
    const int c = p*32 + (tid >> 3);
    const int q = tid & 7;
    const bf16x8 v = *(const bf16x8*)&sT[c*64 + ((q ^ (c & 7)) * 8)];
    *(bf16x8*)(tT + ((size_t)b*CH + c)*HW + j0 + q*8) = v;
  }
}

// ---------- main: y[i] = sum_j relu(xn_i . xn_j)^2 * t[j]  (per batch) ----------
// grid 392 = 49 i-tiles x 8 batches (XCD x <- batch x); 256 thr = 4 waves; 80 KB LDS ->
// 2 BLOCKS/CU co-resident: each SIMD runs 2 waves from DIFFERENT blocks, so one block's
// barrier/stage-drain overlaps the other's MFMAs (the r8-r12 plateau was 1-block lockstep).
// i-tile 64 (3136 = 49*64 exact, no padding). Single-buffer sXJ/sTJ + dbuf sPB:
//   iter k: PV(k-1) [sTJ, sPB[(k-1)&1]]; QK(k) [sXJ]; T12; publish sPB[k&1];
//           barrier; STAGE_XN(k+1) + STAGE_TT(k); barrier (drain).
// QK roles (wj=wid>>1, wi=wid&1): S^T[32j][32i], xn_I in regs. PV roles (ih=wid>>1,
// ch=wid&1): Y[32i][128c], accY[4] (64 regs). D-layout: i=l31, c=rmap(r,hi).
__global__ __launch_bounds__(256) void ppm_main(const u16* __restrict__ xn,
                                                const u16* __restrict__ tT,
                                                float* __restrict__ out){
  __shared__ u16 SM[40960];   // 80 KB: sXJ@0 (16384), sTJ@16384 (16384), sPB[2]@32768/36864 (4096 each)

  const int bid = blockIdx.x;
  const int swz = (bid & 7)*49 + (bid >> 3);
  const int b = swz / 49;          // == bid & 7 (XCD-local batch)
  const int it = swz % 49;

  const int tid = threadIdx.x, wid = tid >> 6, lane = tid & 63;
  const int l31 = lane & 31, hi = lane >> 5;
  const int i0 = it * 64;
  const int wj = wid >> 1, wi = wid & 1;   // QK role
  const int ih = wid >> 1, ch = wid & 1;   // PV role

  // QK B-frags: xn_I rows (col = i = l31), full K=256 (16 ksteps)
  bf16x8 aq[16];
  {
    const u16* p = xn + ((size_t)b*HW + i0 + wi*32 + l31)*CH + hi*8;
    #pragma unroll
    for (int ks = 0; ks < 16; ++ks) aq[ks] = *(const bf16x8*)(p + ks*16);
  }

  f32x16 accY[4];   // [cb]: Y[i = i0 + ih*32 + l31][c = ch*128 + cb*32 + rmap(r,hi)]
  #pragma unroll
  for (int cb = 0; cb < 4; ++cb) accY[cb] = zero16();

  const size_t xbase = (size_t)b*HW;
  const size_t tbase = (size_t)b*CH;

  // stage xn tile jt into sXJ (single buffer); 16-period chunk swizzle (32 chunks/row)
  auto STAGE_XN = [&](int jt){
    u16* dst = SM;
    const int j0n = jt*64;
    #pragma unroll
    for (int q = 0; q < 8; ++q){
      const int m = q*256 + tid;
      const int row = m >> 5, g = m & 31;
      gload16(xn + (xbase + j0n + row)*CH + ((g ^ (row & 15))*8), &dst[m*8]);
    }
  };
  // stage tT tile jt into sTJ (single buffer); 8-period swizzle (8 chunks/row)
  auto STAGE_TT = [&](int jt){
    u16* dst = SM + 16384;
    const int j0n = jt*64;
    #pragma unroll
    for (int q = 0; q < 8; ++q){
      const int m = q*256 + tid;
      const int c = m >> 3, g = m & 7;
      gload16(tT + (tbase + c)*HW + j0n + ((g ^ (c & 7))*8), &dst[m*8]);
    }
  };

  // PV for tile p: consumes sTJ (holds tile p) and sPB[p&1]; wave owns Y[32i(ih)][128c(ch)]
  auto PV = [&](int p){
    const u16* sTJp = SM + 16384;
    const u16* sPBp = SM + 32768 + (p & 1)*4096;
    bf16x8 pb[4];
    #pragma unroll
    for (int ks = 0; ks < 4; ++ks)
      pb[ks] = *(const bf16x8*)&sPBp[(ih*4 + ks)*512 + lane*8];
    __builtin_amdgcn_s_setprio(1);
    #pragma unroll
    for (int ks = 0; ks < 4; ++ks){
      #pragma unroll
      for (int cb = 0; cb < 4; ++cb){
        const int c = ch*128 + cb*32 + l31;
        const bf16x8 af = *(const bf16x8*)&sTJp[c*64 + (((ks*2 + hi) ^ (c & 7)) * 8)];
        accY[cb] = MFMA32(af, pb[ks], accY[cb]);
      }
    }
    __builtin_amdgcn_s_setprio(0);
  };

  // ---- prologue: stage xn(0) ----
  STAGE_XN(0);
  __syncthreads();

  #pragma unroll 1
  for (int jt = 0; jt < NJT; ++jt){
    // ---- PV(jt-1): previous tile (sTJ staged last iter, sPB[(jt-1)&1]) ----
    if (jt > 0) PV(jt - 1);

    // ---- QK(jt): S^T[32j][32i] = sXJ(rows j) x aq, dual chains; 16-period swizzle ----
    f32x16 sa = zero16(), sb = zero16();
    const int rj = wj*32 + l31;
    const int rsw = rj & 15;
    const u16* xjrow = &SM[rj*256];
    __builtin_amdgcn_s_setprio(1);
    #pragma unroll
    for (int kb = 0; kb < 8; ++kb){
      const bf16x8 a0 = *(const bf16x8*)&xjrow[(((kb*4 + hi)     ^ rsw) * 8)];
      const bf16x8 a1 = *(const bf16x8*)&xjrow[(((kb*4 + 2 + hi) ^ rsw) * 8)];
      sa = MFMA32(a0, aq[2*kb],   sa);
      sb = MFMA32(a1, aq[2*kb+1], sb);
    }
    __builtin_amdgcn_s_setprio(0);

    // ---- S in-register: relu^2 -> bf16 pairs -> permlane32_swap -> PV B-frags ----
    float s0,s1,s2,s3,s4,s5,s6,s7,s8,s9,s10,s11,s12,s13,s14,s15;
#define SREL(d, r) { float v_ = sa[r] + sb[r]; v_ = fmaxf(v_, 0.f); d = v_ * v_; }
    SREL(s0,0) SREL(s1,1) SREL(s2,2) SREL(s3,3) SREL(s4,4) SREL(s5,5) SREL(s6,6) SREL(s7,7)
    SREL(s8,8) SREL(s9,9) SREL(s10,10) SREL(s11,11) SREL(s12,12) SREL(s13,13) SREL(s14,14) SREL(s15,15)
#undef SREL
    u32 w0,w1,w2,w3,w4,w5,w6,w7;
#define PK(d, a, c) asm("v_cvt_pk_bf16_f32 %0, %1, %2" : "=v"(d) : "v"(a), "v"(c));
    PK(w0, s0, s1)  PK(w1, s2, s3)  PK(w2, s4, s5)  PK(w3, s6, s7)
    PK(w4, s8, s9)  PK(w5, s10,s11) PK(w6, s12,s13) PK(w7, s14,s15)
#undef PK
    // swap: after this, frag kstep(2wj+0) = [w0,w1,w2,w3], kstep(2wj+1) = [w4,w5,w6,w7]
    asm volatile("v_permlane32_swap_b32 %0, %1" : "+v"(w0), "+v"(w2));
    asm volatile("v_permlane32_swap_b32 %0, %1" : "+v"(w1), "+v"(w3));
    asm volatile("v_permlane32_swap_b32 %0, %1" : "+v"(w4), "+v"(w6));
    asm volatile("v_permlane32_swap_b32 %0, %1" : "+v"(w5), "+v"(w7));
    union { u32 u[4]; bf16x8 v; } fb0, fb1;
    fb0.u[0]=w0; fb0.u[1]=w1; fb0.u[2]=w2; fb0.u[3]=w3;
    fb1.u[0]=w4; fb1.u[1]=w5; fb1.u[2]=w6; fb1.u[3]=w7;

    // publish this wave's two ksteps into sPB[jt&1]: slot = ib*4 + ks, ib = wi, ks = 2wj+s
    u16* sPBk = SM + 32768 + (jt & 1)*4096;
    *(bf16x8*)&sPBk[(wi*4 + 2*wj + 0)*512 + lane*8] = fb0.v;
    *(bf16x8*)&sPBk[(wi*4 + 2*wj + 1)*512 + lane*8] = fb1.v;

    __syncthreads();   // sXJ/sTJ reads done, publish visible

    // ---- stage xn(jt+1) and tT(jt) into the (now free) single buffers ----
    if (jt + 1 < NJT) STAGE_XN(jt + 1);
    STAGE_TT(jt);

    __syncthreads();   // drain staging: sXJ=tile jt+1, sTJ=tile jt ready
  }

  // ---- epilogue: PV for the last tile (sTJ = tile 48, sPB[48&1 = 0]) ----
  PV(NJT - 1);
  __syncthreads();   // all LDS reads done before Yl overwrites SM

  // ---- E-phase: transpose via LDS (each (i,c) has a unique owner), coalesced store ----
  float* Yl = (float*)SM;   // f32 [64][256] = 64 KB, c XOR-swizzled by ((i&7)<<2)
  {
    const int il = ih*32 + l31;      // i-offset = lane l31 (D col)
    const int isw = (il & 7) << 2;
    #pragma unroll
    for (int cb = 0; cb < 4; ++cb)
      #pragma unroll
      for (int r = 0; r < 16; ++r){
        const int c = ch*128 + cb*32 + (r & 3) + 8*(r >> 2) + 4*hi;  // c-offset = rmap (D row)
        Yl[il*256 + (c ^ isw)] = accY[cb][r];
      }
  }
  __syncthreads();
  // coalesced float4 store: thread t -> row i = t>>2, c-quarter (t&3)*64
  {
    const int i3 = tid >> 2;
    const int cq4 = (tid & 3) * 64;
    const int sw3 = (i3 & 7) << 2;
    float* orow = out + ((size_t)b*HW + i0 + i3)*CH;
    #pragma unroll
    for (int q = 0; q < 16; ++q){
      const int c = cq4 + q*4;
      const float4 v = *(const float4*)&Yl[i3*256 + (c ^ sw3)];
      *(float4*)&orow[c] = v;
    }
  }
}

extern "C" void kernel_launch(void* const* d_in, const int* in_sizes, int n_in,
                              void* d_out, int out_size, void* d_ws, size_t ws_size,
                              hipStream_t stream){
  const float* x = (const float*)d_in[0];
  const float* W = (const float*)d_in[1];
  float* out = (float*)d_out;
  char* ws = (char*)d_ws;

  const size_t SZ = (size_t)NPIX * CH * sizeof(u16);   // 12,845,056 bytes
  u16* xn_bf = (u16*)(ws);
  u16* tT    = (u16*)(ws + SZ);
  u16* Wt    = (u16*)(ws + 2*SZ);

  prep_wt<<<CH, CH, 0, stream>>>(W, Wt);
  gemm_t<<<dim3(NJT, 8), 256, 0, stream>>>(x, Wt, xn_bf, tT);
  ppm_main<<<392, 256, 0, stream>>>(xn_bf, tT, out);
}

// Round 14
// 149.693 us; speedup vs baseline: 1.5813x; 1.5813x over previous
//
#include <hip/hip_runtime.h>

#define HW 3136
#define CH 256
#define NJT 49
#define NIT 25
#define NPIX 25088  // 8*3136

typedef __attribute__((ext_vector_type(8))) short bf16x8;
typedef __attribute__((ext_vector_type(4))) float f32x4;
typedef __attribute__((ext_vector_type(16))) float f32x16;
typedef unsigned short u16;
typedef unsigned int u32;

static __device__ __forceinline__ u16 f2bf(float f){
  union { float f; u32 u; } v; v.f = f;
  u32 r = v.u + 0x7FFFu + ((v.u >> 16) & 1u);
  return (u16)(r >> 16);
}

static __device__ __forceinline__ void gload16(const void* g, void* l){
  __builtin_amdgcn_global_load_lds(
      (const __attribute__((address_space(1))) unsigned int*)g,
      (__attribute__((address_space(3))) unsigned int*)l, 16, 0, 0);
}

static __device__ __forceinline__ f32x16 zero16(){
  f32x16 v;
  #pragma unroll
  for (int e = 0; e < 16; ++e) v[e] = 0.f;
  return v;
}

#define MFMA32(A,B,C) __builtin_amdgcn_mfma_f32_32x32x16_bf16((A),(B),(C),0,0,0)

// ---------- prep: W (CxC fp32, [cin][cout]) -> Wt bf16 [cout][cin] ----------
__global__ __launch_bounds__(256) void prep_wt(const float* __restrict__ W,
                                               u16* __restrict__ Wt){
  const int o = blockIdx.x, i = threadIdx.x;
  Wt[o*CH + i] = f2bf(W[i*CH + o]);
}

// ---------- fused: row-norm (fp32) + xn emit + t = x @ W stored transposed tT[b][c][j] ----------
__global__ __launch_bounds__(256) void gemm_t(const float* __restrict__ x,
                                              const u16* __restrict__ Wt,
                                              u16* __restrict__ xn_bf,
                                              u16* __restrict__ tT){
  __shared__ u16 sT[256*64];  // [c][j-chunk swizzled]
  const int jt = blockIdx.x, b = blockIdx.y;
  const int tid = threadIdx.x, wid = tid >> 6, lane = tid & 63;
  const int l15 = lane & 15, l4 = lane >> 4;
  const int j0 = jt * 64;
  const int row = j0 + wid*16 + l15;
  const float* xp = x + ((size_t)b*HW + row)*CH + l4*8;

  float xv[8][8];
  float ss = 0.f;
  #pragma unroll
  for (int kb = 0; kb < 8; ++kb){
    const float4 v0 = *(const float4*)(xp + kb*32);
    const float4 v1 = *(const float4*)(xp + kb*32 + 4);
    xv[kb][0]=v0.x; xv[kb][1]=v0.y; xv[kb][2]=v0.z; xv[kb][3]=v0.w;
    xv[kb][4]=v1.x; xv[kb][5]=v1.y; xv[kb][6]=v1.z; xv[kb][7]=v1.w;
    #pragma unroll
    for (int e = 0; e < 8; ++e) ss += xv[kb][e]*xv[kb][e];
  }
  ss += __shfl_xor(ss, 16);
  ss += __shfl_xor(ss, 32);
  const float inv = rsqrtf(fmaxf(ss, 1e-12f));

  bf16x8 ax[8];
  #pragma unroll
  for (int kb = 0; kb < 8; ++kb){
    bf16x8 a, n;
    #pragma unroll
    for (int e = 0; e < 8; ++e){
      a[e] = (short)f2bf(xv[kb][e]);
      n[e] = (short)f2bf(xv[kb][e]*inv);
    }
    ax[kb] = a;
    *(bf16x8*)(xn_bf + ((size_t)b*HW + row)*CH + kb*32 + l4*8) = n;
  }

  f32x4 acc[16];
  #pragma unroll
  for (int n = 0; n < 16; ++n) acc[n] = f32x4{0.f,0.f,0.f,0.f};
  #pragma unroll
  for (int kb = 0; kb < 8; ++kb){
    #pragma unroll
    for (int n0 = 0; n0 < 16; ++n0){
      const bf16x8 bb = *(const bf16x8*)(Wt + (n0*16 + l15)*CH + kb*32 + l4*8);
      acc[n0] = __builtin_amdgcn_mfma_f32_16x16x32_bf16(ax[kb], bb, acc[n0], 0, 0, 0);
    }
  }
  #pragma unroll
  for (int n0 = 0; n0 < 16; ++n0){
    const int c = n0*16 + l15;
    const int jloc = wid*16 + l4*4;
    const int gj = jloc >> 3;
    ushort4 w4;
    w4.x = f2bf(acc[n0][0]); w4.y = f2bf(acc[n0][1]);
    w4.z = f2bf(acc[n0][2]); w4.w = f2bf(acc[n0][3]);
    *(ushort4*)&sT[c*64 + ((gj ^ (c & 7)) * 8) + (jloc & 7)] = w4;
  }
  __syncthreads();
  #pragma unroll
  for (int p = 0; p < 8; ++p){
    const int c = p*32 + (tid >> 3);
    const int q = tid & 7;
    const bf16x8 v = *(const bf16x8*)&sT[c*64 + ((q ^ (c & 7)) * 8)];
    *(bf16x8*)(tT + ((size_t)b*CH + c)*HW + j0 + q*8) = v;
  }
}

// ---------- main: y[i] = sum_j relu(xn_i . xn_j)^2 * t[j]  (per batch) ----------
// grid (25, 8); 512 threads = 8 waves; 144 KB LDS, i-tile 128.  [BEST VERIFIED: r8, 119.3 us]
// wave (wj = wid>>2, wi = wid&3): QK computes S^T[32j(wj)][32i(wi)] (swapped, B = xn_I regs);
// S in registers -> relu^2 -> cvt_pk bf16 -> permlane32_swap -> PV B-frags (T12);
// frags published to sPB (16 KB), each wave consumes ALL 4 ksteps for its own
// output quarter Y[32i(wi)][128c(wj)] -> accY[4] (64 regs). PV D-layout: lane l31 = i-offset,
// rmap(r,hi) = c-offset -> E-phase LDS transpose for coalesced store.
__global__ __launch_bounds__(512) void ppm_main(const u16* __restrict__ xn,
                                                const u16* __restrict__ tT,
                                                float* __restrict__ out){
  __shared__ u16 SM[73728];   // 144 KB: tiles dbuf 2x(sXJ 16384 + sTJ 16384 u16) + sPB 8192 u16; E-phase: Yl f32[128][256]

  const int it = blockIdx.x, b = blockIdx.y;
  const int tid = threadIdx.x, wid = tid >> 6, lane = tid & 63;
  const int l31 = lane & 31, hi = lane >> 5;
  const int i0 = it * 128;
  const int wj = wid >> 2, wi = wid & 3;
  u16* sPB = SM + 65536;   // [slot = wi*4 + ks][lane] 16B frags

  // QK B-frags: xn_I rows (col = i = l31), full K=256 (16 ksteps)
  bf16x8 aq[16];
  {
    int irow = i0 + wi*32 + l31;
    if (irow >= HW) irow = HW - 1;   // pad rows (it=24): duplicate, store-guarded
    const u16* p = xn + ((size_t)b*HW + irow)*CH + hi*8;
    #pragma unroll
    for (int ks = 0; ks < 16; ++ks) aq[ks] = *(const bf16x8*)(p + ks*16);
  }

  f32x16 accY[4];   // Y quarter: [cb][r] -> Y[i = wi*32 + l31][c = wj*128 + cb*32 + rmap(r,hi)]
  #pragma unroll
  for (int cb = 0; cb < 4; ++cb) accY[cb] = zero16();

  const size_t xbase = (size_t)b*HW;
  const size_t tbase = (size_t)b*CH;

  // ---- prologue: stage J-tile 0 into buffer 0 ----
  {
    u16* nXJ = SM;
    u16* nTJ = SM + 16384;
    #pragma unroll
    for (int q = 0; q < 4; ++q){
      const int m = q*512 + tid;
      { const int row = m >> 5, g = m & 31;
        gload16(xn + (xbase + row)*CH + ((g ^ (row & 7))*8), &nXJ[m*8]); }
      { const int c = m >> 3, g = m & 7;
        gload16(tT + (tbase + c)*HW + ((g ^ (c & 7))*8), &nTJ[m*8]); }
    }
    __syncthreads();
  }

  #pragma unroll 1
  for (int jt = 0; jt < NJT; ++jt){
    const int buf = jt & 1;
    u16* sXJ = SM + buf*32768;
    u16* sTJ = sXJ + 16384;

    // ---- stage next J-tile (issued first; drained by the mid-iter barrier) ----
    if (jt + 1 < NJT){
      u16* nXJ = SM + (buf ^ 1)*32768;
      u16* nTJ = nXJ + 16384;
      const int j0n = (jt + 1)*64;
      #pragma unroll
      for (int q = 0; q < 4; ++q){
        const int m = q*512 + tid;
        { const int row = m >> 5, g = m & 31;
          gload16(xn + (xbase + j0n + row)*CH + ((g ^ (row & 7))*8), &nXJ[m*8]); }
        { const int c = m >> 3, g = m & 7;
          gload16(tT + (tbase + c)*HW + j0n + ((g ^ (c & 7))*8), &nTJ[m*8]); }
      }
    }

    // ---- QK: S^T[32j][32i] = sXJ(rows j) x aq, dual chains ----
    f32x16 sa = zero16(), sb = zero16();
    const int rj = wj*32 + l31;
    const int rsw = rj & 7;
    const u16* xjrow = &sXJ[rj*256];
    __builtin_amdgcn_s_setprio(1);
    #pragma unroll
    for (int kb = 0; kb < 8; ++kb){
      const bf16x8 a0 = *(const bf16x8*)&xjrow[(((kb*4 + hi)     ^ rsw) * 8)];
      const bf16x8 a1 = *(const bf16x8*)&xjrow[(((kb*4 + 2 + hi) ^ rsw) * 8)];
      sa = MFMA32(a0, aq[2*kb],   sa);
      sb = MFMA32(a1, aq[2*kb+1], sb);
    }
    __builtin_amdgcn_s_setprio(0);

    // ---- S in-register: relu^2 -> bf16 pairs -> permlane32_swap -> PV B-frags ----
    float s0,s1,s2,s3,s4,s5,s6,s7,s8,s9,s10,s11,s12,s13,s14,s15;
#define SREL(d, r) { float v_ = sa[r] + sb[r]; v_ = fmaxf(v_, 0.f); d = v_ * v_; }
    SREL(s0,0) SREL(s1,1) SREL(s2,2) SREL(s3,3) SREL(s4,4) SREL(s5,5) SREL(s6,6) SREL(s7,7)
    SREL(s8,8) SREL(s9,9) SREL(s10,10) SREL(s11,11) SREL(s12,12) SREL(s13,13) SREL(s14,14) SREL(s15,15)
#undef SREL
    u32 w0,w1,w2,w3,w4,w5,w6,w7;
#define PK(d, a, c) asm("v_cvt_pk_bf16_f32 %0, %1, %2" : "=v"(d) : "v"(a), "v"(c));
    PK(w0, s0, s1)  PK(w1, s2, s3)  PK(w2, s4, s5)  PK(w3, s6, s7)
    PK(w4, s8, s9)  PK(w5, s10,s11) PK(w6, s12,s13) PK(w7, s14,s15)
#undef PK
    // swap: after this, frag kstep(2wj+0) = [w0,w1,w2,w3], kstep(2wj+1) = [w4,w5,w6,w7]
    asm volatile("v_permlane32_swap_b32 %0, %1" : "+v"(w0), "+v"(w2));
    asm volatile("v_permlane32_swap_b32 %0, %1" : "+v"(w1), "+v"(w3));
    asm volatile("v_permlane32_swap_b32 %0, %1" : "+v"(w4), "+v"(w6));
    asm volatile("v_permlane32_swap_b32 %0, %1" : "+v"(w5), "+v"(w7));
    union { u32 u[4]; bf16x8 v; } fb0, fb1;
    fb0.u[0]=w0; fb0.u[1]=w1; fb0.u[2]=w2; fb0.u[3]=w3;
    fb1.u[0]=w4; fb1.u[1]=w5; fb1.u[2]=w6; fb1.u[3]=w7;

    // publish this wave's two ksteps (16B/lane each, conflict-free)
    *(bf16x8*)&sPB[(wi*4 + 2*wj + 0)*512 + lane*8] = fb0.v;
    *(bf16x8*)&sPB[(wi*4 + 2*wj + 1)*512 + lane*8] = fb1.v;
    __syncthreads();   // sPB visible; also drains staged loads (issued at iter top)

    // ---- PV: Y[32i][128c] per wave, full j-sum: 4 ksteps x 4 cb ----
    bf16x8 pb[4];
    #pragma unroll
    for (int ks = 0; ks < 4; ++ks)
      pb[ks] = *(const bf16x8*)&sPB[(wi*4 + ks)*512 + lane*8];

    __builtin_amdgcn_s_setprio(1);
    #pragma unroll
    for (int ks = 0; ks < 4; ++ks){
      #pragma unroll
      for (int cb = 0; cb < 4; ++cb){
        const int c = wj*128 + cb*32 + l31;
        const bf16x8 af = *(const bf16x8*)&sTJ[c*64 + (((ks*2 + hi) ^ (c & 7)) * 8)];
        accY[cb] = MFMA32(af, pb[ks], accY[cb]);
      }
    }
    __builtin_amdgcn_s_setprio(0);

    __syncthreads();   // protects tile buf + sPB for next iteration
  }

  // ---- E-phase: transpose via LDS (each (i,c) has a unique owner), coalesced store ----
  float* Yl = (float*)SM;   // f32 [128][256], c XOR-swizzled by ((i&7)<<2)
  {
    const int il = wi*32 + l31;      // i-offset = lane l31 (D col)
    const int isw = (il & 7) << 2;
    #pragma unroll
    for (int cb = 0; cb < 4; ++cb)
      #pragma unroll
      for (int r = 0; r < 16; ++r){
        const int c = wj*128 + cb*32 + (r & 3) + 8*(r >> 2) + 4*hi;   // c-offset = rmap(r,hi) (D row)
        Yl[il*256 + (c ^ isw)] = accY[cb][r];
      }
  }
  __syncthreads();
  // coalesced float4 store: thread t -> row i = t>>2, c-quarter (t&3)*64
  {
    const int i3 = tid >> 2;
    const int cq = (tid & 3) * 64;
    const int sw3 = (i3 & 7) << 2;
    if (i0 + i3 < HW){
      float* orow = out + ((size_t)b*HW + i0 + i3)*CH;
      #pragma unroll
      for (int q = 0; q < 16; ++q){
        const int c = cq + q*4;
        const float4 v = *(const float4*)&Yl[i3*256 + (c ^ sw3)];
        *(float4*)&orow[c] = v;
      }
    }
  }
}

extern "C" void kernel_launch(void* const* d_in, const int* in_sizes, int n_in,
                              void* d_out, int out_size, void* d_ws, size_t ws_size,
                              hipStream_t stream){
  const float* x = (const float*)d_in[0];
  const float* W = (const float*)d_in[1];
  float* out = (float*)d_out;
  char* ws = (char*)d_ws;

  const size_t SZ = (size_t)NPIX * CH * sizeof(u16);   // 12,845,056 bytes
  u16* xn_bf = (u16*)(ws);
  u16* tT    = (u16*)(ws + SZ);
  u16* Wt    = (u16*)(ws + 2*SZ);

  prep_wt<<<CH, CH, 0, stream>>>(W, Wt);
  gemm_t<<<dim3(NJT, 8), 256, 0, stream>>>(x, Wt, xn_bf, tT);
  ppm_main<<<dim3(NIT, 8), 512, 0, stream>>>(xn_bf, tT, out);
}